// Round 1
// baseline (357.068 us; speedup 1.0000x reference)
//
#include <hip/hip_runtime.h>

#define MAX_PATH_DISTANCE 5

// Pass 1: scatter packed keys with atomicMax so that the highest edge index
// wins per cell (== last-write-wins in edge order, matching numpy scatter).
// key = ((e+1) << 3) | bidx ; key==0 means "no edge touched this cell".
__global__ void se_scatter_keys(const int* __restrict__ src,
                                const int* __restrict__ dst,
                                const int* __restrict__ plen,
                                unsigned int* __restrict__ out,
                                int E, int N) {
    int e = blockIdx.x * blockDim.x + threadIdx.x;
    if (e >= E) return;
    int s  = src[e];
    int d  = dst[e];
    int pl = plen[e];
    int bidx = (pl < 1 ? 1 : (pl > MAX_PATH_DISTANCE ? MAX_PATH_DISTANCE : pl)) - 1;
    unsigned int key = ((unsigned int)(e + 1) << 3) | (unsigned int)bidx;
    atomicMax(&out[(size_t)s * (size_t)N + (size_t)d], key);
}

// Pass 2: each edge checks whether it won its cell; the unique winner
// overwrites the key with the actual float value b[bidx].
__global__ void se_resolve(const int* __restrict__ src,
                           const int* __restrict__ dst,
                           const int* __restrict__ plen,
                           const float* __restrict__ b,
                           unsigned int* __restrict__ out,
                           int E, int N) {
    int e = blockIdx.x * blockDim.x + threadIdx.x;
    if (e >= E) return;
    int s  = src[e];
    int d  = dst[e];
    int pl = plen[e];
    int bidx = (pl < 1 ? 1 : (pl > MAX_PATH_DISTANCE ? MAX_PATH_DISTANCE : pl)) - 1;
    unsigned int key = ((unsigned int)(e + 1) << 3) | (unsigned int)bidx;
    size_t off = (size_t)s * (size_t)N + (size_t)d;
    if (out[off] == key) {
        reinterpret_cast<float*>(out)[off] = b[bidx];
    }
}

extern "C" void kernel_launch(void* const* d_in, const int* in_sizes, int n_in,
                              void* d_out, int out_size, void* d_ws, size_t ws_size,
                              hipStream_t stream) {
    // setup_inputs order: x [N,128] f32, b [5] f32, src [E] int, dst [E] int, path_len [E] int
    const float* b    = (const float*)d_in[1];
    const int*   src  = (const int*)d_in[2];
    const int*   dst  = (const int*)d_in[3];
    const int*   plen = (const int*)d_in[4];

    const int N = in_sizes[0] / 128;   // 8192
    const int E = in_sizes[2];         // 4,000,000

    // Zero the output (also the atomicMax init state). Graph-capture safe.
    hipMemsetAsync(d_out, 0, (size_t)out_size * sizeof(float), stream);

    const int block = 256;
    const int grid  = (E + block - 1) / block;
    se_scatter_keys<<<grid, block, 0, stream>>>(src, dst, plen,
                                                (unsigned int*)d_out, E, N);
    se_resolve<<<grid, block, 0, stream>>>(src, dst, plen, b,
                                           (unsigned int*)d_out, E, N);
}